// Round 9
// baseline (4274.742 us; speedup 1.0000x reference)
//
#include <hip/hip_runtime.h>

#define THREADS 256
#define T_TOT 432
#define T_IN  144
#define T_OUT 288

// LDS float4-granule offsets (R6 extents; PART region gone)
#define WS4     1552            // per-mat W stride (f4)
#define HA_OFF  4656            // 3*1552
#define HB_OFF  6704            // HA_OFF + 2048
#define PRJ_OFFf 35008          // (HB_OFF+2048)*4 (float index)
#define LDS_BYTES 141056        // (PRJ_OFFf+256)*4

// ws layout (floats): h1b0 [0,64K) h1b1 [64K,128K) h2b0 [128K,192K) h2b1 [192K,256K)
//   (global h layout: [k=256][b=256]) — exchanged via sc0/sc1 (MALL-coherent) ops only
// counters: 512 uints at ws+262144; group bt: cntA = +bt*64, cntB = +bt*64+32 (relaxed RMW only)

#define FMA4(a,h,s) { a.x=fmaf((h).x,(s),a.x); a.y=fmaf((h).y,(s),a.y); \
                      a.z=fmaf((h).z,(s),a.z); a.w=fmaf((h).w,(s),a.w); }

#define VMWAIT() do { asm volatile("s_waitcnt vmcnt(0)" ::: "memory"); \
                      __builtin_amdgcn_sched_barrier(0); } while(0)

__device__ __forceinline__ float sigf(float x){ return 1.0f/(1.0f + __expf(-x)); }
__device__ __forceinline__ float tanhfast(float x){ return 1.0f - 2.0f/(__expf(2.0f*x)+1.0f); }

template<int CTRL>
__device__ __forceinline__ float4 dpp_add(float4 v){
  float4 r;
  r.x = v.x + __int_as_float(__builtin_amdgcn_update_dpp(0, __float_as_int(v.x), CTRL, 0xf, 0xf, true));
  r.y = v.y + __int_as_float(__builtin_amdgcn_update_dpp(0, __float_as_int(v.y), CTRL, 0xf, 0xf, true));
  r.z = v.z + __int_as_float(__builtin_amdgcn_update_dpp(0, __float_as_int(v.z), CTRL, 0xf, 0xf, true));
  r.w = v.w + __int_as_float(__builtin_amdgcn_update_dpp(0, __float_as_int(v.w), CTRL, 0xf, 0xf, true));
  return r;
}
// full 16-lane K-reduction: xor1, xor2 (quad_perm), xor4 (ROW_HALF_MIRROR ^7,
// valid once bits0-1 uniform), xor8 (ROW_MIRROR ^15, valid once bits0-2 uniform)
__device__ __forceinline__ float4 kred16(float4 v){
  v = dpp_add<177>(v);     // quad_perm [1,0,3,2]
  v = dpp_add<78>(v);      // quad_perm [2,3,0,1]
  v = dpp_add<0x141>(v);   // ROW_HALF_MIRROR
  v = dpp_add<0x140>(v);   // ROW_MIRROR
  return v;
}

extern "C" __global__ void gru_init(float* __restrict__ ws, float* __restrict__ out,
                                    const float* __restrict__ b_proj){
  int i = blockIdx.x*THREADS + threadIdx.x;
  if (i < 262144) ws[i] = 0.0f;
  if (i < 512) ((unsigned*)(ws + 262144))[i] = 0u;
  if (i < 73728) out[i] = b_proj[0];
}

typedef float v4f __attribute__((ext_vector_type(4)));

extern "C" __global__ void __launch_bounds__(THREADS, 1) gru_persist(
    const float* __restrict__ x,
    const float* __restrict__ wih0, const float* __restrict__ whh0,
    const float* __restrict__ bih0, const float* __restrict__ bhh0,
    const float* __restrict__ wih1, const float* __restrict__ whh1,
    const float* __restrict__ bih1, const float* __restrict__ bhh1,
    const float* __restrict__ wproj,
    float* __restrict__ out, float* __restrict__ ws)
{
  extern __shared__ float lds[];
  float4* WL4 = (float4*)lds;
  float4* HA4 = WL4 + HA_OFF;
  float4* HB4 = WL4 + HB_OFF;
  const float* HAf = (const float*)HA4;
  const float* HBf = (const float*)HB4;
  float* PRJ = lds + PRJ_OFFf;

  const int tid = threadIdx.x;
  const int bt  = blockIdx.x & 7;     // batch tile (XCD-local group)
  const int g   = blockIdx.x >> 3;    // hidden slice (8 rows)
  // GEMM lane roles: 16-way K in-lane (bits 0-3), quad-lo bits 4-5, wave = [rh|qghi]
  const int kg   = tid & 15;          // k4 in [4kg, 4kg+4), k in [16kg, 16kg+16)
  const int qglo = (tid >> 4) & 3;
  const int wv   = tid >> 6;
  const int rh   = wv >> 1;           // row half: hh in [4rh, 4rh+4) per gate
  const int cq   = ((wv & 1) << 2) | qglo;   // col quad 0..7
  // owner cell lies inside this thread's own tile (lane-local extraction)
  const int hrow = (rh << 2) | (kg >> 2);    // 0..7
  const int col  = (cq << 2) | (kg & 3);     // 0..31
  const int rowg = g*8 + hrow;
  const int btb  = bt << 5;

  float* h1b0 = ws;
  float* h1b1 = ws + 65536;
  float* h2b0 = ws + 131072;
  float* h2b1 = ws + 196608;
  unsigned* cntA = ((unsigned*)(ws + 262144)) + (bt << 6);
  unsigned* cntB = cntA + 32;

  // ---- one-time: W slices -> LDS [k4*24 + row + (k4>>2)] (kg-spread skew) ----
  {
    const float* srcs[3] = {whh0, wih1, whh1};
    #pragma unroll
    for (int m = 0; m < 3; m++){
      const float* S = srcs[m];
      for (int i = 0; i < 6; i++){
        int idx = tid + (i << 8);
        int row = idx % 24;              // gate*8 + hh
        int k4  = idx / 24;              // 0..63
        int gate = row >> 3, hh = row & 7;
        float4 v = *(const float4*)(S + (gate*256 + g*8 + hh)*256 + (k4 << 2));
        WL4[m*WS4 + k4*24 + row + (k4 >> 2)] = v;
      }
    }
  }
  // owner-side small weights
  float wi0[3][10];
  float bi0g[3], bh0g[3], bi1g[3], bh1g[3];
  #pragma unroll
  for (int G = 0; G < 3; G++){
    #pragma unroll
    for (int d = 0; d < 10; d++) wi0[G][d] = wih0[(G*256 + rowg)*10 + d];
    bi0g[G] = bih0[G*256 + rowg];
    bh0g[G] = bhh0[G*256 + rowg];
    bi1g[G] = bih1[G*256 + rowg];
    bh1g[G] = bhh1[G*256 + rowg];
  }
  const float wp = wproj[rowg];
  // owner readback into H tile: layout addr4(k,q) = 8k + ((q + (k>>4)) & 7)
  const int hIdx = (rowg << 5) + ((((col >> 2) + (rowg >> 4)) & 7) << 2) + (col & 3);

  v4f hreg[8];
  auto SLOADC = [&](const float* __restrict__ hg){
    #pragma unroll
    for (int i = 0; i < 8; i++){
      int idx = tid + (i << 8);
      const float* p = hg + ((idx >> 3) << 8) + btb + ((idx & 7) << 2);
      asm volatile("global_load_dwordx4 %0, %1, off sc0 sc1"
                   : "=v"(hreg[i]) : "v"(p) : "memory");
    }
  };
  auto SWRITE = [&](float4* __restrict__ H4){
    #pragma unroll
    for (int i = 0; i < 8; i++){
      int idx = tid + (i << 8);
      int k = idx >> 3, q = idx & 7;
      *(v4f*)&H4[(k << 3) + ((q + (k >> 4)) & 7)] = hreg[i];
    }
  };
  auto HSTORE = [&](float* p, float v){
    asm volatile("global_store_dword %0, %1, off sc0 sc1" :: "v"(p), "v"(v) : "memory");
  };

  // ---- GEMM: 12 rows x 1 quad x 16 k per thread; 48 W + 16 H b128 reads ----
  auto GEMM3 = [&](const float4* __restrict__ H4, int m, float4 (&acc)[3][4]){
    const int wb = m*WS4;
    #pragma unroll
    for (int j = 0; j < 4; j++){
      const int k4 = (kg << 2) + j;
      const int wr = wb + k4*24 + (k4 >> 2);   // k4>>2 == kg
      float4 wf[3][4];
      #pragma unroll
      for (int gte = 0; gte < 3; gte++)
        #pragma unroll
        for (int ri = 0; ri < 4; ri++)
          wf[gte][ri] = WL4[wr + (gte << 3) + (rh << 2) + ri];
      #pragma unroll
      for (int dk = 0; dk < 4; dk++){
        const int kidx = (k4 << 2) + dk;       // kidx>>4 == kg
        float4 hv = H4[(kidx << 3) + ((cq + kg) & 7)];
        #pragma unroll
        for (int gte = 0; gte < 3; gte++)
          #pragma unroll
          for (int ri = 0; ri < 4; ri++){
            float wsv = dk == 0 ? wf[gte][ri].x : dk == 1 ? wf[gte][ri].y :
                        dk == 2 ? wf[gte][ri].z : wf[gte][ri].w;
            FMA4(acc[gte][ri], hv, wsv);
          }
      }
    }
  };
  // reduce all 12 accs over the 16 kg lanes, then extract owner's 3 gate values
  auto REDEX = [&](float4 (&acc)[3][4], float* g3){
    #pragma unroll
    for (int gte = 0; gte < 3; gte++)
      #pragma unroll
      for (int ri = 0; ri < 4; ri++)
        acc[gte][ri] = kred16(acc[gte][ri]);
    const int r = kg >> 2, c = kg & 3;
    #pragma unroll
    for (int gte = 0; gte < 3; gte++){
      float4 f0 = (r & 2) ? acc[gte][2] : acc[gte][0];
      float4 f1 = (r & 2) ? acc[gte][3] : acc[gte][1];
      float4 f  = (r & 1) ? f1 : f0;
      float e0 = (c & 2) ? f.z : f.x;
      float e1 = (c & 2) ? f.w : f.y;
      g3[gte] = (c & 1) ? e1 : e0;
    }
  };

  auto WAIT = [&](unsigned* c, unsigned tgt){
    while (__hip_atomic_fetch_add(c, 0u, __ATOMIC_RELAXED, __HIP_MEMORY_SCOPE_AGENT) < tgt)
      __builtin_amdgcn_s_sleep(4);
  };
  auto ARRIVE = [&](unsigned* c){
    __hip_atomic_fetch_add(c, 1u, __ATOMIC_RELAXED, __HIP_MEMORY_SCOPE_AGENT);
  };

  __syncthreads();
  SLOADC(h1b1);                        // h1[-1] = 0
  VMWAIT();
  SWRITE(HA4);
  __syncthreads();

  for (int t = 0; t < T_TOT; t++){
    const float* h2prev = (t & 1) ? h2b0 : h2b1;
    float* h1nxt = (t & 1) ? h1b1 : h1b0;
    float* h2nxt = (t & 1) ? h2b1 : h2b0;

    if (tid == 0) WAIT(cntB, 32u*(unsigned)t);
    __syncthreads();                                          // bar1
    SLOADC(h2prev);                    // in flight under GEMM0

    // ---------------- layer 0: whh0 . h1[t-1] (HA resident) ----------------
    float4 acc0[3][4] = {};
    GEMM3(HA4, 0, acc0);
    float g0[3];
    REDEX(acc0, g0);
    float xr = bi0g[0], xz = bi0g[1], xn = bi0g[2];
    if (t < T_IN){
      const float* xp = x + (btb + col)*(T_IN*10) + t*10;
      #pragma unroll
      for (int d = 0; d < 10; d++){
        float xvv = xp[d];
        xr = fmaf(wi0[0][d], xvv, xr);
        xz = fmaf(wi0[1][d], xvv, xz);
        xn = fmaf(wi0[2][d], xvv, xn);
      }
    }
    float r = sigf(xr + g0[0] + bh0g[0]);
    float z = sigf(xz + g0[1] + bh0g[1]);
    float n = tanhfast(xn + r*(g0[2] + bh0g[2]));
    float hnew1 = fmaf(z, HAf[hIdx] - n, n);
    HSTORE(h1nxt + (rowg << 8) + btb + col, hnew1);
    VMWAIT();                          // h2prev tile arrived + h1 store acked
    SWRITE(HB4);
    __syncthreads();                                          // bar2
    if (tid == 0) ARRIVE(cntA);

    // ---------------- layer 1 part A: whh1 . h2[t-1] ----------------
    float4 acc2[3][4] = {};
    GEMM3(HB4, 2, acc2);
    float g2[3];
    REDEX(acc2, g2);
    if (tid == 0) WAIT(cntA, 32u*(unsigned)(t + 1));
    __syncthreads();                                          // bar3
    SLOADC(h1nxt);
    VMWAIT();                          // h1[t] tile arrived
    SWRITE(HA4);                       // feeds GEMM1 now, GEMM0 next step
    __syncthreads();                                          // bar4

    // ---------------- layer 1 part B: wih1 . h1[t] ----------------
    float4 acc1[3][4] = {};
    GEMM3(HA4, 1, acc1);
    float g1[3];
    REDEX(acc1, g1);
    float r1 = sigf(g1[0] + bi1g[0] + g2[0] + bh1g[0]);
    float z1 = sigf(g1[1] + bi1g[1] + g2[1] + bh1g[1]);
    float n1 = tanhfast(g1[2] + bi1g[2] + r1*(g2[2] + bh1g[2]));
    float h2new = fmaf(z1, HBf[hIdx] - n1, n1);
    HSTORE(h2nxt + (rowg << 8) + btb + col, h2new);
    if (t >= T_IN) PRJ[(hrow << 5) + col] = h2new * wp;
    VMWAIT();                          // h2 store acked
    __syncthreads();                                          // bar5
    if (tid == 0) ARRIVE(cntB);

    if (t >= T_IN && tid < 32){
      float s = 0.0f;
      #pragma unroll
      for (int hh = 0; hh < 8; hh++) s += PRJ[hh*32 + tid];
      atomicAdd(out + (btb + tid)*T_OUT + (t - T_IN), s);
    }
  }
}

extern "C" void kernel_launch(void* const* d_in, const int* in_sizes, int n_in,
                              void* d_out, int out_size, void* d_ws, size_t ws_size,
                              hipStream_t stream){
  const float* x     = (const float*)d_in[0];
  const float* wih0  = (const float*)d_in[1];
  const float* whh0  = (const float*)d_in[2];
  const float* bih0  = (const float*)d_in[3];
  const float* bhh0  = (const float*)d_in[4];
  const float* wih1  = (const float*)d_in[5];
  const float* whh1  = (const float*)d_in[6];
  const float* bih1  = (const float*)d_in[7];
  const float* bhh1  = (const float*)d_in[8];
  const float* wproj = (const float*)d_in[9];
  const float* bproj = (const float*)d_in[10];
  float* out = (float*)d_out;
  float* ws  = (float*)d_ws;

  hipLaunchKernelGGL(gru_init, dim3(1024), dim3(THREADS), 0, stream, ws, out, bproj);

  hipFuncSetAttribute(reinterpret_cast<const void*>(gru_persist),
                      hipFuncAttributeMaxDynamicSharedMemorySize, LDS_BYTES);

  void* args[] = {
    (void*)&x, (void*)&wih0, (void*)&whh0, (void*)&bih0, (void*)&bhh0,
    (void*)&wih1, (void*)&whh1, (void*)&bih1, (void*)&bhh1,
    (void*)&wproj, (void*)&out, (void*)&ws
  };
  hipLaunchCooperativeKernel(reinterpret_cast<void*>(gru_persist),
                             dim3(256), dim3(THREADS), args, LDS_BYTES, stream);
}

// Round 13
// 3788.388 us; speedup vs baseline: 1.1284x; 1.1284x over previous
//
#include <hip/hip_runtime.h>

#define THREADS 256
#define T_TOT 432
#define T_IN  144
#define T_OUT 288

// LDS float4-granule offsets (R9 layout, unchanged)
#define WS4     1552            // per-mat W stride (f4)
#define HA_OFF  4656            // 3*1552
#define HB_OFF  6704            // HA_OFF + 2048
#define PRJ_OFFf 35008          // (HB_OFF+2048)*4 (float index)
#define LDS_BYTES 141056        // (PRJ_OFFf+256)*4

// ws layout (floats): h1b0 [0,64K) h1b1 [64K,128K) h2b0 [128K,192K) h2b1 [192K,256K)
//   (global h layout: [k=256][b=256]) — exchanged via sc0/sc1 (MALL-coherent) ops only
// counters: 512 uints at ws+262144; group bt: cntA = +bt*64, cntB = +bt*64+32 (relaxed RMW only)
// R13 = R9 (passing) + PKFMA GEMM ONLY. No other diffs — bisection round.

typedef float v2f __attribute__((ext_vector_type(2)));
union f4u { float4 f; v2f h[2]; };

// packed fp32 fma: acc(2) += h(2) * broadcast(w-component)
#define PKFMA_LO(acc, hh, w2) asm("v_pk_fma_f32 %0, %1, %2, %0 op_sel:[0,0,0] op_sel_hi:[1,0,1]" \
                                  : "+v"(acc) : "v"(hh), "v"(w2))
#define PKFMA_HI(acc, hh, w2) asm("v_pk_fma_f32 %0, %1, %2, %0 op_sel:[0,1,0] op_sel_hi:[1,1,1]" \
                                  : "+v"(acc) : "v"(hh), "v"(w2))

#define VMWAIT0() do { asm volatile("s_waitcnt vmcnt(0)" ::: "memory"); \
                       __builtin_amdgcn_sched_barrier(0); } while(0)

__device__ __forceinline__ float sigf(float x){ return 1.0f/(1.0f + __expf(-x)); }
__device__ __forceinline__ float tanhfast(float x){ return 1.0f - 2.0f/(__expf(2.0f*x)+1.0f); }

template<int CTRL>
__device__ __forceinline__ float4 dpp_add(float4 v){
  float4 r;
  r.x = v.x + __int_as_float(__builtin_amdgcn_update_dpp(0, __float_as_int(v.x), CTRL, 0xf, 0xf, true));
  r.y = v.y + __int_as_float(__builtin_amdgcn_update_dpp(0, __float_as_int(v.y), CTRL, 0xf, 0xf, true));
  r.z = v.z + __int_as_float(__builtin_amdgcn_update_dpp(0, __float_as_int(v.z), CTRL, 0xf, 0xf, true));
  r.w = v.w + __int_as_float(__builtin_amdgcn_update_dpp(0, __float_as_int(v.w), CTRL, 0xf, 0xf, true));
  return r;
}
// full 16-lane K-reduction (proven in R9)
__device__ __forceinline__ float4 kred16(float4 v){
  v = dpp_add<177>(v);     // quad_perm [1,0,3,2]
  v = dpp_add<78>(v);      // quad_perm [2,3,0,1]
  v = dpp_add<0x141>(v);   // ROW_HALF_MIRROR (xor4; valid, bits0-1 uniform)
  v = dpp_add<0x140>(v);   // ROW_MIRROR (xor8)
  return v;
}

extern "C" __global__ void gru_init(float* __restrict__ ws, float* __restrict__ out,
                                    const float* __restrict__ b_proj){
  int i = blockIdx.x*THREADS + threadIdx.x;
  if (i < 262144) ws[i] = 0.0f;
  if (i < 512) ((unsigned*)(ws + 262144))[i] = 0u;
  if (i < 73728) out[i] = b_proj[0];
}

typedef float v4f __attribute__((ext_vector_type(4)));

extern "C" __global__ void __launch_bounds__(THREADS, 1) gru_persist(
    const float* __restrict__ x,
    const float* __restrict__ wih0, const float* __restrict__ whh0,
    const float* __restrict__ bih0, const float* __restrict__ bhh0,
    const float* __restrict__ wih1, const float* __restrict__ whh1,
    const float* __restrict__ bih1, const float* __restrict__ bhh1,
    const float* __restrict__ wproj,
    float* __restrict__ out, float* __restrict__ ws)
{
  extern __shared__ float lds[];
  float4* WL4 = (float4*)lds;
  float4* HA4 = WL4 + HA_OFF;
  float4* HB4 = WL4 + HB_OFF;
  const float* HAf = (const float*)HA4;
  const float* HBf = (const float*)HB4;
  float* PRJ = lds + PRJ_OFFf;

  const int tid = threadIdx.x;
  const int bt  = blockIdx.x & 7;     // batch tile (XCD-local group)
  const int g   = blockIdx.x >> 3;    // hidden slice (8 rows)
  const int kg   = tid & 15;          // 16-way K split (in-wave)
  const int wv   = tid >> 6;
  const int rh   = wv >> 1;           // row half
  const int cq   = ((wv & 1) << 2) | ((tid >> 4) & 3);   // col quad 0..7
  // owner cell (lane-local extraction, proven R9)
  const int hrow = (rh << 2) | (kg >> 2);
  const int col  = (cq << 2) | (kg & 3);
  const int rowg = g*8 + hrow;
  const int btb  = bt << 5;

  float* h1b0 = ws;
  float* h1b1 = ws + 65536;
  float* h2b0 = ws + 131072;
  float* h2b1 = ws + 196608;
  unsigned* cntA = ((unsigned*)(ws + 262144)) + (bt << 6);
  unsigned* cntB = cntA + 32;

  // ---- one-time: W slices -> LDS [k4*24 + row + (k4>>2)] ----
  {
    const float* srcs[3] = {whh0, wih1, whh1};
    #pragma unroll
    for (int m = 0; m < 3; m++){
      const float* S = srcs[m];
      for (int i = 0; i < 6; i++){
        int idx = tid + (i << 8);
        int row = idx % 24;
        int k4  = idx / 24;
        int gate = row >> 3, hh = row & 7;
        float4 v = *(const float4*)(S + (gate*256 + g*8 + hh)*256 + (k4 << 2));
        WL4[m*WS4 + k4*24 + row + (k4 >> 2)] = v;
      }
    }
  }
  float wi0[3][10];
  float bi0g[3], bh0g[3], bi1g[3], bh1g[3];
  #pragma unroll
  for (int G = 0; G < 3; G++){
    #pragma unroll
    for (int d = 0; d < 10; d++) wi0[G][d] = wih0[(G*256 + rowg)*10 + d];
    bi0g[G] = bih0[G*256 + rowg];
    bh0g[G] = bhh0[G*256 + rowg];
    bi1g[G] = bih1[G*256 + rowg];
    bh1g[G] = bhh1[G*256 + rowg];
  }
  const float wp = wproj[rowg];
  const int hIdx = (rowg << 5) + ((((col >> 2) + (rowg >> 4)) & 7) << 2) + (col & 3);

  v4f hreg[8];
  auto SLOADC = [&](const float* __restrict__ hg){
    #pragma unroll
    for (int i = 0; i < 8; i++){
      int idx = tid + (i << 8);
      const float* p = hg + ((idx >> 3) << 8) + btb + ((idx & 7) << 2);
      asm volatile("global_load_dwordx4 %0, %1, off sc0 sc1"
                   : "=v"(hreg[i]) : "v"(p) : "memory");
    }
  };
  auto SWRITE = [&](float4* __restrict__ H4){
    #pragma unroll
    for (int i = 0; i < 8; i++){
      int idx = tid + (i << 8);
      int k = idx >> 3, q = idx & 7;
      *(v4f*)&H4[(k << 3) + ((q + (k >> 4)) & 7)] = hreg[i];
    }
  };
  auto HSTORE = [&](float* p, float v){
    asm volatile("global_store_dword %0, %1, off sc0 sc1" :: "v"(p), "v"(v) : "memory");
  };

  // ---- GEMM: 12 rows x 1 quad x 16 k; R9 addressing, packed v_pk_fma_f32 ----
  auto GEMM3 = [&](const float4* __restrict__ H4, int m, f4u (&acc)[3][4]){
    const int wb = m*WS4;
    #pragma unroll
    for (int j = 0; j < 4; j++){
      const int k4 = (kg << 2) + j;
      const int wr = wb + k4*24 + (k4 >> 2);   // skew k4>>2 == kg
      f4u wf[3][4];
      #pragma unroll
      for (int gte = 0; gte < 3; gte++)
        #pragma unroll
        for (int ri = 0; ri < 4; ri++)
          wf[gte][ri].f = WL4[wr + (gte << 3) + (rh << 2) + ri];
      #pragma unroll
      for (int dk = 0; dk < 4; dk++){
        const int kidx = (k4 << 2) + dk;
        f4u hv; hv.f = H4[(kidx << 3) + ((cq + kg) & 7)];
        #pragma unroll
        for (int gte = 0; gte < 3; gte++)
          #pragma unroll
          for (int ri = 0; ri < 4; ri++){
            v2f w2 = wf[gte][ri].h[dk >> 1];   // (x,y) for dk 0/1, (z,w) for dk 2/3
            if ((dk & 1) == 0){
              PKFMA_LO(acc[gte][ri].h[0], hv.h[0], w2);
              PKFMA_LO(acc[gte][ri].h[1], hv.h[1], w2);
            } else {
              PKFMA_HI(acc[gte][ri].h[0], hv.h[0], w2);
              PKFMA_HI(acc[gte][ri].h[1], hv.h[1], w2);
            }
          }
      }
    }
  };
  auto ZERO = [&](f4u (&acc)[3][4]){
    #pragma unroll
    for (int a1 = 0; a1 < 3; a1++)
      #pragma unroll
      for (int a2 = 0; a2 < 4; a2++){ float4 z = {0,0,0,0}; acc[a1][a2].f = z; }
  };
  auto REDEX = [&](f4u (&acc)[3][4], float* g3){
    #pragma unroll
    for (int gte = 0; gte < 3; gte++)
      #pragma unroll
      for (int ri = 0; ri < 4; ri++)
        acc[gte][ri].f = kred16(acc[gte][ri].f);
    const int r = kg >> 2, c = kg & 3;
    #pragma unroll
    for (int gte = 0; gte < 3; gte++){
      float4 f0 = (r & 2) ? acc[gte][2].f : acc[gte][0].f;
      float4 f1 = (r & 2) ? acc[gte][3].f : acc[gte][1].f;
      float4 f  = (r & 1) ? f1 : f0;
      float e0 = (c & 2) ? f.z : f.x;
      float e1 = (c & 2) ? f.w : f.y;
      g3[gte] = (c & 1) ? e1 : e0;
    }
  };

  auto WAIT = [&](unsigned* c, unsigned tgt){
    while (__hip_atomic_fetch_add(c, 0u, __ATOMIC_RELAXED, __HIP_MEMORY_SCOPE_AGENT) < tgt)
      __builtin_amdgcn_s_sleep(4);
  };
  auto ARRIVE = [&](unsigned* c){
    __hip_atomic_fetch_add(c, 1u, __ATOMIC_RELAXED, __HIP_MEMORY_SCOPE_AGENT);
  };

  __syncthreads();
  SLOADC(h1b1);                        // h1[-1] = 0
  VMWAIT0();
  SWRITE(HA4);
  __syncthreads();

  for (int t = 0; t < T_TOT; t++){
    const float* h2prev = (t & 1) ? h2b0 : h2b1;
    float* h1nxt = (t & 1) ? h1b1 : h1b0;
    float* h2nxt = (t & 1) ? h2b1 : h2b0;

    if (tid == 0) WAIT(cntB, 32u*(unsigned)t);
    __syncthreads();                                          // bar1
    SLOADC(h2prev);                    // in flight under GEMM0

    // ---------------- layer 0: whh0 . h1[t-1] (HA resident) ----------------
    f4u acc0[3][4]; ZERO(acc0);
    GEMM3(HA4, 0, acc0);
    float g0[3];
    REDEX(acc0, g0);
    float xr = bi0g[0], xz = bi0g[1], xn = bi0g[2];
    if (t < T_IN){
      const float* xp = x + (btb + col)*(T_IN*10) + t*10;
      #pragma unroll
      for (int d = 0; d < 10; d++){
        float xvv = xp[d];
        xr = fmaf(wi0[0][d], xvv, xr);
        xz = fmaf(wi0[1][d], xvv, xz);
        xn = fmaf(wi0[2][d], xvv, xn);
      }
    }
    float r = sigf(xr + g0[0] + bh0g[0]);
    float z = sigf(xz + g0[1] + bh0g[1]);
    float n = tanhfast(xn + r*(g0[2] + bh0g[2]));
    float hnew1 = fmaf(z, HAf[hIdx] - n, n);
    HSTORE(h1nxt + (rowg << 8) + btb + col, hnew1);
    VMWAIT0();                         // h2prev tile arrived + h1 store acked
    SWRITE(HB4);
    __syncthreads();                                          // bar2
    if (tid == 0) ARRIVE(cntA);

    // ---------------- layer 1 part A: whh1 . h2[t-1] ----------------
    f4u acc2[3][4]; ZERO(acc2);
    GEMM3(HB4, 2, acc2);
    float g2[3];
    REDEX(acc2, g2);
    if (tid == 0) WAIT(cntA, 32u*(unsigned)(t + 1));
    __syncthreads();                                          // bar3
    SLOADC(h1nxt);
    VMWAIT0();                         // h1[t] tile arrived
    SWRITE(HA4);                       // feeds GEMM1 now, GEMM0 next step
    __syncthreads();                                          // bar4

    // ---------------- layer 1 part B: wih1 . h1[t] ----------------
    f4u acc1[3][4]; ZERO(acc1);
    GEMM3(HA4, 1, acc1);
    float g1[3];
    REDEX(acc1, g1);
    float r1 = sigf(g1[0] + bi1g[0] + g2[0] + bh1g[0]);
    float z1 = sigf(g1[1] + bi1g[1] + g2[1] + bh1g[1]);
    float n1 = tanhfast(g1[2] + bi1g[2] + r1*(g2[2] + bh1g[2]));
    float h2new = fmaf(z1, HBf[hIdx] - n1, n1);
    HSTORE(h2nxt + (rowg << 8) + btb + col, h2new);
    if (t >= T_IN) PRJ[(hrow << 5) + col] = h2new * wp;
    VMWAIT0();                         // h2 store acked
    __syncthreads();                                          // bar5
    if (tid == 0) ARRIVE(cntB);

    if (t >= T_IN && tid < 32){
      float s = 0.0f;
      #pragma unroll
      for (int hh = 0; hh < 8; hh++) s += PRJ[hh*32 + tid];
      atomicAdd(out + (btb + tid)*T_OUT + (t - T_IN), s);
    }
  }
}

extern "C" void kernel_launch(void* const* d_in, const int* in_sizes, int n_in,
                              void* d_out, int out_size, void* d_ws, size_t ws_size,
                              hipStream_t stream){
  const float* x     = (const float*)d_in[0];
  const float* wih0  = (const float*)d_in[1];
  const float* whh0  = (const float*)d_in[2];
  const float* bih0  = (const float*)d_in[3];
  const float* bhh0  = (const float*)d_in[4];
  const float* wih1  = (const float*)d_in[5];
  const float* whh1  = (const float*)d_in[6];
  const float* bih1  = (const float*)d_in[7];
  const float* bhh1  = (const float*)d_in[8];
  const float* wproj = (const float*)d_in[9];
  const float* bproj = (const float*)d_in[10];
  float* out = (float*)d_out;
  float* ws  = (float*)d_ws;

  hipLaunchKernelGGL(gru_init, dim3(1024), dim3(THREADS), 0, stream, ws, out, bproj);

  hipFuncSetAttribute(reinterpret_cast<const void*>(gru_persist),
                      hipFuncAttributeMaxDynamicSharedMemorySize, LDS_BYTES);

  void* args[] = {
    (void*)&x, (void*)&wih0, (void*)&whh0, (void*)&bih0, (void*)&bhh0,
    (void*)&wih1, (void*)&whh1, (void*)&bih1, (void*)&bhh1,
    (void*)&wproj, (void*)&out, (void*)&ws
  };
  hipLaunchCooperativeKernel(reinterpret_cast<void*>(gru_persist),
                             dim3(256), dim3(THREADS), args, LDS_BYTES, stream);
}